// Round 17
// baseline (280.481 us; speedup 1.0000x reference)
//
#include <hip/hip_runtime.h>
#include <hip/hip_fp16.h>
#include <math.h>

#define DD 64      // per-head channels
#define HH 8       // heads
#define HD 512     // HH*DD
#define NC 1024    // combined xl|xr row width

typedef __attribute__((ext_vector_type(8))) short bf16x8;
typedef __attribute__((ext_vector_type(4))) float f32x4;
typedef __attribute__((ext_vector_type(8))) unsigned short ushort8;

// ---------------------------------------------------------------------------
// bf16 split helpers (round-to-nearest-even)
// ---------------------------------------------------------------------------
__device__ __forceinline__ ushort bf16_rne(float f) {
    uint u = __float_as_uint(f);
    u += 0x7fffu + ((u >> 16) & 1u);
    return (ushort)(u >> 16);
}
__device__ __forceinline__ float bf16_tof(ushort h) {
    return __uint_as_float(((uint)h) << 16);
}
// packed fp16 max — ROCm 7.2 headers lack __hmax2; emit v_pk_max_f16 directly
__device__ __forceinline__ __half2 pk_max(__half2 a, __half2 b) {
    __half2 r;
    asm("v_pk_max_f16 %0, %1, %2" : "=v"(r) : "v"(a), "v"(b));
    return r;
}

// ---------------------------------------------------------------------------
// Fused prep: [split_mat | split_wT(K=64) | split_wT(K=512) | hist_deg]
// sectioned by blockIdx — one launch instead of four (kills 3 launch gaps).
// ---------------------------------------------------------------------------
__global__ __launch_bounds__(256) void prep(
    const float* __restrict__ x,
    const float* __restrict__ Wl1, const float* __restrict__ Wr1,
    const float* __restrict__ Wl2, const float* __restrict__ Wr2,
    const int* __restrict__ dsts,
    ushort* __restrict__ xs_h, ushort* __restrict__ xs_l,
    ushort* __restrict__ bt1_h, ushort* __restrict__ bt1_l,
    ushort* __restrict__ bt2_h, ushort* __restrict__ bt2_l,
    int* __restrict__ deg,
    int N, int E, int ET, int nb_sm, int nb_w1, int nb_w2)
{
    const int b   = blockIdx.x;
    const int tid = threadIdx.x;

    if (b < nb_sm) {                       // x -> bf16 hi/lo (N*64, exact)
        const int i = b * 256 + tid;
        const float f = x[i];
        const ushort h = bf16_rne(f);
        xs_h[i] = h;
        xs_l[i] = bf16_rne(f - bf16_tof(h));
    } else if (b < nb_sm + nb_w1) {        // W1 -> Bt1 (1024x64, exact)
        const int i = (b - nb_sm) * 256 + tid;        // i = c*64 + k
        const int c = i >> 6, k = i & 63;
        const float* W = (c < 512) ? Wl1 : Wr1;
        const float f = W[(size_t)k * 512 + (c & 511)];
        const ushort h = bf16_rne(f);
        bt1_h[i] = h;
        bt1_l[i] = bf16_rne(f - bf16_tof(h));
    } else if (b < nb_sm + nb_w1 + nb_w2) {// W2 -> Bt2 (1024x512, exact)
        const int i = (b - nb_sm - nb_w1) * 256 + tid; // i = c*512 + k
        const int c = i >> 9, k = i & 511;
        const float* W = (c < 512) ? Wl2 : Wr2;
        const float f = W[(size_t)k * 512 + (c & 511)];
        const ushort h = bf16_rne(f);
        bt2_h[i] = h;
        bt2_l[i] = bf16_rne(f - bf16_tof(h));
    } else {                               // degree histogram (ET, guarded)
        const int w = (b - nb_sm - nb_w1 - nb_w2) * 256 + tid;
        if (w < ET) {
            const int d = (w < E) ? dsts[w] : (w - E);   // virtual self-loop
            atomicAdd(&deg[d], 1);
        }
    }
}

// ---------------------------------------------------------------------------
// bf16x3 split-precision MFMA GEMM (round-12 proven version, 65 us @ K=512).
// Staging via global_load_lds width=16; LDS dest linear, XOR swizzle applied
// to the GLOBAL source chunk (m173 pattern): LDS(row,c) = G(row, c^(row&7)).
// ---------------------------------------------------------------------------
__global__ __launch_bounds__(256) void gemm_bf16x3(
    const ushort* __restrict__ Ah, const ushort* __restrict__ Al,
    const ushort* __restrict__ Bh, const ushort* __restrict__ Bl,
    __half* __restrict__ C, int M, int K)
{
    __shared__ __align__(16) ushort lAh[128 * 64];
    __shared__ __align__(16) ushort lAl[128 * 64];
    __shared__ __align__(16) ushort lBh[128 * 64];
    __shared__ __align__(16) ushort lBl[128 * 64];

    const int nwg = gridDim.x;                        // 8*MT, divisible by 8
    const int wg  = (blockIdx.x & 7) * (nwg >> 3) + (blockIdx.x >> 3);
    const int ntile = wg & 7, mtile = wg >> 3;
    const int bm = mtile * 128, bn = ntile * 128;

    const int tid  = threadIdx.x;
    const int wid  = tid >> 6;            // 0..3
    const int lane = tid & 63;
    const int wr = wid >> 1, wc = wid & 1;   // 2x2 wave quadrants (64x64)
    const int l15 = lane & 15, g = lane >> 4;

    const int rsub = lane >> 3;              // row within 8-row group (0..7)
    const int gch  = (lane & 7) ^ rsub;      // pre-swizzled source k-chunk

    f32x4 acc[4][4] = {};

    for (int k0 = 0; k0 < K; k0 += 64) {
        __syncthreads();                   // previous iter's LDS reads done
        #pragma unroll
        for (int q = 0; q < 4; ++q) {
            const int rowb = wid * 32 + q * 8;        // wave-uniform base row
            const int row  = rowb + rsub;
            const size_t ga = (size_t)min(bm + row, M - 1) * K + k0 + gch * 8;
            const size_t gb = (size_t)(bn + row) * K + k0 + gch * 8;
            __builtin_amdgcn_global_load_lds(
                (const __attribute__((address_space(1))) void*)(Ah + ga),
                (__attribute__((address_space(3))) void*)(lAh + rowb * 64), 16, 0, 0);
            __builtin_amdgcn_global_load_lds(
                (const __attribute__((address_space(1))) void*)(Al + ga),
                (__attribute__((address_space(3))) void*)(lAl + rowb * 64), 16, 0, 0);
            __builtin_amdgcn_global_load_lds(
                (const __attribute__((address_space(1))) void*)(Bh + gb),
                (__attribute__((address_space(3))) void*)(lBh + rowb * 64), 16, 0, 0);
            __builtin_amdgcn_global_load_lds(
                (const __attribute__((address_space(1))) void*)(Bl + gb),
                (__attribute__((address_space(3))) void*)(lBl + rowb * 64), 16, 0, 0);
        }
        __syncthreads();                   // drains vmcnt (compiler-emitted)

        #pragma unroll
        for (int kk = 0; kk < 2; ++kk) {
            bf16x8 ah[4], al[4], bh[4], bl[4];
            #pragma unroll
            for (int m = 0; m < 4; ++m) {
                const int row = wr * 64 + m * 16 + l15;
                const int sc  = (kk * 4 + g) ^ (row & 7);
                const int idx = row * 64 + (sc << 3);
                ah[m] = *(const bf16x8*)(lAh + idx);
                al[m] = *(const bf16x8*)(lAl + idx);
            }
            #pragma unroll
            for (int n = 0; n < 4; ++n) {
                const int row = wc * 64 + n * 16 + l15;
                const int sc  = (kk * 4 + g) ^ (row & 7);
                const int idx = row * 64 + (sc << 3);
                bh[n] = *(const bf16x8*)(lBh + idx);
                bl[n] = *(const bf16x8*)(lBl + idx);
            }
            #pragma unroll
            for (int m = 0; m < 4; ++m)
                #pragma unroll
                for (int n = 0; n < 4; ++n) {
                    acc[m][n] = __builtin_amdgcn_mfma_f32_16x16x32_bf16(
                                    ah[m], bh[n], acc[m][n], 0, 0, 0);
                    acc[m][n] = __builtin_amdgcn_mfma_f32_16x16x32_bf16(
                                    ah[m], bl[n], acc[m][n], 0, 0, 0);
                    acc[m][n] = __builtin_amdgcn_mfma_f32_16x16x32_bf16(
                                    al[m], bh[n], acc[m][n], 0, 0, 0);
                }
        }
    }

    #pragma unroll
    for (int m = 0; m < 4; ++m) {
        #pragma unroll
        for (int i = 0; i < 4; ++i) {
            const int row = bm + wr * 64 + m * 16 + g * 4 + i;
            if (row >= M) continue;
            __half* cp = C + (size_t)row * NC + bn + wc * 64 + l15;
            #pragma unroll
            for (int n = 0; n < 4; ++n)
                cp[n * 16] = __float2half_rn(acc[m][n][i]);
        }
    }
}

// ---------------------------------------------------------------------------
// CSR build: scan + scatter (hist fused into prep).
// ---------------------------------------------------------------------------
__global__ __launch_bounds__(1024) void scan_rowptr(const int* __restrict__ deg,
                                                    int* __restrict__ rowptr,
                                                    int* __restrict__ cursor, int n)
{
    __shared__ int sums[1024];
    const int tid   = threadIdx.x;
    const int chunk = (n + 1023) / 1024;
    const int lo = min(tid * chunk, n), hi = min(lo + chunk, n);

    int s = 0;
    for (int i = lo; i < hi; ++i) s += deg[i];
    sums[tid] = s;
    __syncthreads();

    for (int off = 1; off < 1024; off <<= 1) {
        const int t = (tid >= off) ? sums[tid - off] : 0;
        __syncthreads();
        sums[tid] += t;
        __syncthreads();
    }

    int run = sums[tid] - s;   // exclusive prefix of this chunk
    for (int i = lo; i < hi; ++i) {
        rowptr[i] = run;
        cursor[i] = run;
        run += deg[i];
    }
    if (tid == 1023) rowptr[n] = run;   // == ET
}

__global__ __launch_bounds__(256) void scatter_csr(const int* __restrict__ srcs,
                                                   const int* __restrict__ dsts,
                                                   int E, int ET,
                                                   int* __restrict__ cursor,
                                                   int* __restrict__ eidx)
{
    const int w = blockIdx.x * blockDim.x + threadIdx.x;
    if (w >= ET) return;
    int s, d;
    if (w < E) { s = srcs[w]; d = dsts[w]; }
    else       { s = w - E;   d = s; }
    const int pos = atomicAdd(&cursor[d], 1);
    eidx[pos] = s;
}

// ---------------------------------------------------------------------------
// Fused GATv2 edge pipeline + epilogue.
// ONE wave per dst node; lane owns 8 contiguous channels (head = lane>>3).
// Packed-fp16 logit path; 4-deep software-pipelined gather: row loads for
// group g+1 issue at iteration start from already-resident indices, while
// indices for group g+2 load concurrently (64B/wave in flight).
// ---------------------------------------------------------------------------
__device__ __forceinline__ void edge_step_pk(const ushort8 v,
                                             const __half2* __restrict__ ra,
                                             const __half2* __restrict__ at,
                                             const __half2 c02,
                                             float* __restrict__ acc, float& den)
{
    float vf[8];
    __half2 sacc = __floats2half2_rn(0.f, 0.f);
    #pragma unroll
    for (int j = 0; j < 4; ++j) {
        ushort2 u = make_ushort2(v[2 * j], v[2 * j + 1]);
        const __half2 vh = *reinterpret_cast<const __half2*>(&u);
        const float2 vv = __half22float2(vh);
        vf[2 * j] = vv.x; vf[2 * j + 1] = vv.y;
        __half2 t = __hadd2(vh, ra[j]);
        t = pk_max(t, __hmul2(t, c02));           // leaky_relu(0.2), both signs
        sacc = __hfma2(t, at[j], sacc);
    }
    float s = __low2float(sacc) + __high2float(sacc);
    s += __shfl_xor(s, 1, 64);                    // reduce within 8-lane head
    s += __shfl_xor(s, 2, 64);
    s += __shfl_xor(s, 4, 64);
    const float p = __expf(s);                    // logits O(1): no max shift
    den += p;
    #pragma unroll
    for (int j = 0; j < 8; ++j) acc[j] = fmaf(p, vf[j], acc[j]);
}

template<int MODE>
__global__ __launch_bounds__(256) void gat_fused(
    const __half* __restrict__ xlr, const float* __restrict__ att,
    const float* __restrict__ bias, const int* __restrict__ rowptr,
    const int* __restrict__ eidx, int n, float* __restrict__ out,
    ushort* __restrict__ oh, ushort* __restrict__ ol)
{
    const int d    = (blockIdx.x * blockDim.x + threadIdx.x) >> 6;
    const int lane = threadIdx.x & 63;
    if (d >= n) return;

    const int o = lane * 8;                  // channels [o, o+8)
    const __half2 c02 = __floats2half2_rn(0.2f, 0.2f);

    // xr row (fp16) and att (fp32->fp16) -> packed registers
    __half2 ra[4], at[4];
    {
        const ushort8 rv = *(const ushort8*)((const ushort*)xlr + (size_t)d * NC + 512 + o);
        #pragma unroll
        for (int j = 0; j < 4; ++j) {
            ushort2 u = make_ushort2(rv[2 * j], rv[2 * j + 1]);
            ra[j] = *reinterpret_cast<const __half2*>(&u);
            at[j] = __floats2half2_rn(att[o + 2 * j], att[o + 2 * j + 1]);
        }
    }

    float acc[8] = {};
    float den = 0.f;

    const int start = rowptr[d];
    const int end   = rowptr[d + 1];         // deg >= 1 (self-loop)
    const int last  = end - 1;
    const ushort* xb = (const ushort*)xlr;

    // group A rows (edges start..start+3, clamped) + group B indices
    ushort8 vA0, vA1, vA2, vA3;
    int iB0, iB1, iB2, iB3;
    {
        const int a0 = eidx[start];
        const int a1 = eidx[min(start + 1, last)];
        const int a2 = eidx[min(start + 2, last)];
        const int a3 = eidx[min(start + 3, last)];
        vA0 = *(const ushort8*)(xb + ((size_t)a0 << 10) + o);
        vA1 = *(const ushort8*)(xb + ((size_t)a1 << 10) + o);
        vA2 = *(const ushort8*)(xb + ((size_t)a2 << 10) + o);
        vA3 = *(const ushort8*)(xb + ((size_t)a3 << 10) + o);
        iB0 = eidx[min(start + 4, last)];
        iB1 = eidx[min(start + 5, last)];
        iB2 = eidx[min(start + 6, last)];
        iB3 = eidx[min(start + 7, last)];
    }

    int e = start;
    for (; e + 3 < end; e += 4) {
        // rows for next group (indices already resident)
        const ushort8 vB0 = *(const ushort8*)(xb + ((size_t)iB0 << 10) + o);
        const ushort8 vB1 = *(const ushort8*)(xb + ((size_t)iB1 << 10) + o);
        const ushort8 vB2 = *(const ushort8*)(xb + ((size_t)iB2 << 10) + o);
        const ushort8 vB3 = *(const ushort8*)(xb + ((size_t)iB3 << 10) + o);
        // indices for group after next
        const int nB0 = eidx[min(e + 8,  last)];
        const int nB1 = eidx[min(e + 9,  last)];
        const int nB2 = eidx[min(e + 10, last)];
        const int nB3 = eidx[min(e + 11, last)];

        edge_step_pk(vA0, ra, at, c02, acc, den);
        edge_step_pk(vA1, ra, at, c02, acc, den);
        edge_step_pk(vA2, ra, at, c02, acc, den);
        edge_step_pk(vA3, ra, at, c02, acc, den);

        vA0 = vB0; vA1 = vB1; vA2 = vB2; vA3 = vB3;
        iB0 = nB0; iB1 = nB1; iB2 = nB2; iB3 = nB3;
    }
    // tail: 0..3 edges, vA preloaded with clamped (=valid) indices
    if (e < end)     edge_step_pk(vA0, ra, at, c02, acc, den);
    if (e + 1 < end) edge_step_pk(vA1, ra, at, c02, acc, den);
    if (e + 2 < end) edge_step_pk(vA2, ra, at, c02, acc, den);

    const float inv = 1.f / den;

    if (MODE == 0) {
        // elu(agg + b1), emitted as bf16 hi/lo split for the next GEMM
        float bv[8];
        *(float4*)&bv[0] = *(const float4*)(bias + o);
        *(float4*)&bv[4] = *(const float4*)(bias + o + 4);
        ushort8 hx, lx;
        #pragma unroll
        for (int j = 0; j < 8; ++j) {
            const float u = fmaf(acc[j], inv, bv[j]);
            const float w = u > 0.f ? u : expm1f(u);
            const ushort h = bf16_rne(w);
            hx[j] = h;
            lx[j] = bf16_rne(w - bf16_tof(h));
        }
        *(ushort8*)(oh + (size_t)d * HD + o) = hx;
        *(ushort8*)(ol + (size_t)d * HD + o) = lx;
    } else {
        // mean over 8 heads: reduce across lane bits 3,4,5
        float m[8];
        #pragma unroll
        for (int j = 0; j < 8; ++j) m[j] = acc[j] * inv;
        #pragma unroll
        for (int j = 0; j < 8; ++j) {
            m[j] += __shfl_xor(m[j], 8,  64);
            m[j] += __shfl_xor(m[j], 16, 64);
            m[j] += __shfl_xor(m[j], 32, 64);
        }
        if (lane < 8) {                      // lane covers channels lane*8..+7
            const int c = lane * 8;
            float4 r0, r1;
            r0.x = fmaf(m[0], 0.125f, bias[c + 0]);
            r0.y = fmaf(m[1], 0.125f, bias[c + 1]);
            r0.z = fmaf(m[2], 0.125f, bias[c + 2]);
            r0.w = fmaf(m[3], 0.125f, bias[c + 3]);
            r1.x = fmaf(m[4], 0.125f, bias[c + 4]);
            r1.y = fmaf(m[5], 0.125f, bias[c + 5]);
            r1.z = fmaf(m[6], 0.125f, bias[c + 6]);
            r1.w = fmaf(m[7], 0.125f, bias[c + 7]);
            *(float4*)(out + (size_t)d * DD + c)     = r0;
            *(float4*)(out + (size_t)d * DD + c + 4) = r1;
        }
    }
}

// ---------------------------------------------------------------------------
extern "C" void kernel_launch(void* const* d_in, const int* in_sizes, int n_in,
                              void* d_out, int out_size, void* d_ws, size_t ws_size,
                              hipStream_t stream)
{
    const float* x    = (const float*)d_in[0];
    const int*   ei   = (const int*)  d_in[1];
    const float* Wl1  = (const float*)d_in[2];
    const float* Wr1  = (const float*)d_in[3];
    const float* att1 = (const float*)d_in[4];
    const float* b1   = (const float*)d_in[5];
    const float* Wl2  = (const float*)d_in[6];
    const float* Wr2  = (const float*)d_in[7];
    const float* att2 = (const float*)d_in[8];
    const float* b2   = (const float*)d_in[9];

    const int N  = in_sizes[0] / DD;   // 20000
    const int E  = in_sizes[1] / 2;    // 320000
    const int ET = E + N;              // edges + self-loops

    const int* srcs = ei;
    const int* dsts = ei + E;

    // ---- workspace layout ----
    __half* xlr   = (__half*)d_ws;                      // N*1024 f16 (41 MB)
    ushort* xs_h  = (ushort*)(xlr + (size_t)N * NC);    // N*64
    ushort* xs_l  = xs_h  + (size_t)N * DD;             // N*64
    ushort* h1_h  = xs_l  + (size_t)N * DD;             // N*512
    ushort* h1_l  = h1_h  + (size_t)N * HD;             // N*512
    ushort* bt1_h = h1_l  + (size_t)N * HD;             // 1024*64
    ushort* bt1_l = bt1_h + 1024 * DD;                  // 1024*64
    ushort* bt2_h = bt1_l + 1024 * DD;                  // 1024*512
    ushort* bt2_l = bt2_h + 1024 * HD;                  // 1024*512
    int* rowptr = (int*)(bt2_l + 1024 * HD);            // N+1
    int* deg    = rowptr + (N + 1);                     // N
    int* cursor = deg + N;                              // N
    int* eidx   = cursor + N;                           // ET

    const dim3 gblk(256);
    const int  nblk  = (N + 3) / 4;            // one WAVE per node, 4 nodes/block
    const int  MT    = (N + 127) / 128;        // 157
    const int  gemm_grid = 8 * MT;             // 1256, divisible by 8

    // prep sections (split_mat | wT1 | wT2 | hist) — sizes exact multiples
    const int nb_sm = (N * DD) / 256;          // 5000
    const int nb_w1 = (1024 * DD) / 256;       // 256
    const int nb_w2 = (1024 * HD) / 256;       // 2048
    const int nb_h  = (ET + 255) / 256;

    // ---- prep (splits + degree histogram) + CSR build ----
    hipMemsetAsync(deg, 0, (size_t)N * sizeof(int), stream);
    prep<<<nb_sm + nb_w1 + nb_w2 + nb_h, gblk, 0, stream>>>(
        x, Wl1, Wr1, Wl2, Wr2, dsts, xs_h, xs_l, bt1_h, bt1_l, bt2_h, bt2_l,
        deg, N, E, ET, nb_sm, nb_w1, nb_w2);
    scan_rowptr<<<1, 1024, 0, stream>>>(deg, rowptr, cursor, N);
    scatter_csr<<<nb_h, gblk, 0, stream>>>(srcs, dsts, E, ET, cursor, eidx);

    // ---- layer 1: GATv2Conv(64 -> 64, heads=8, concat) + ELU ----
    gemm_bf16x3<<<gemm_grid, gblk, 0, stream>>>(xs_h, xs_l, bt1_h, bt1_l, xlr, N, DD);
    gat_fused<0><<<nblk, gblk, 0, stream>>>(xlr, att1, b1, rowptr, eidx, N,
                                            nullptr, h1_h, h1_l);

    // ---- layer 2: GATv2Conv(512 -> 64, heads=8, mean) ----
    gemm_bf16x3<<<gemm_grid, gblk, 0, stream>>>(h1_h, h1_l, bt2_h, bt2_l, xlr, N, HD);
    gat_fused<1><<<nblk, gblk, 0, stream>>>(xlr, att2, b2, rowptr, eidx, N,
                                            (float*)d_out, nullptr, nullptr);
}